// Round 1
// baseline (302.079 us; speedup 1.0000x reference)
//
#include <hip/hip_runtime.h>
#include <stdint.h>

#define NB 2
#define NH 12
#define NS 2048
#define ND 64

typedef __attribute__((ext_vector_type(4))) float f32x4;
typedef __attribute__((ext_vector_type(8))) short s16x8;

__device__ __forceinline__ short f2bf(float x) {
    return __builtin_bit_cast(short, (__bf16)x);
}
__device__ __forceinline__ float bf2f(short h) {
    uint32_t u = ((uint32_t)(unsigned short)h) << 16;
    return __builtin_bit_cast(float, u);
}
__device__ __forceinline__ f32x4 mfma16(s16x8 a, s16x8 b, f32x4 c) {
    return __builtin_amdgcn_mfma_f32_16x16x32_bf16(a, b, c, 0, 0, 0);
}

// ---------- pre-pass 1: mask int32 -> bitmask (1 bit / element), 1 MB ----------
__global__ void kbits(const int* __restrict__ maskg, uint32_t* __restrict__ bits) {
    int wi = blockIdx.x * 256 + threadIdx.x;            // word index
    const int* mp = maskg + (size_t)wi * 32;
    uint32_t v = 0;
#pragma unroll
    for (int i = 0; i < 8; i++) {
        int4 q = *(const int4*)(mp + i * 4);
        v |= ((uint32_t)(q.x != 0) << (i * 4)) | ((uint32_t)(q.y != 0) << (i * 4 + 1)) |
             ((uint32_t)(q.z != 0) << (i * 4 + 2)) | ((uint32_t)(q.w != 0) << (i * 4 + 3));
    }
    bits[wi] = v;
}

// ---------- pre-pass 2: VwT[b,h,d,k] = V[b,h,k,d]*w[k] as bf16, 6.3 MB ----------
__global__ void kvwt(const float* __restrict__ Vg, const float* __restrict__ wg,
                     unsigned short* __restrict__ vwt) {
    __shared__ float tile[32][65];
    int blk = blockIdx.x;
    int bh = blk >> 6;
    int k0 = (blk & 63) * 32;
    const float* Vh = Vg + ((size_t)bh * NS + k0) * ND;
    int t = threadIdx.x;
    {
        int kk = t >> 3, c = (t & 7) * 8;
        f32x4 a = *(const f32x4*)(Vh + kk * ND + c);
        f32x4 b4 = *(const f32x4*)(Vh + kk * ND + c + 4);
        float wk = wg[k0 + kk];
#pragma unroll
        for (int j = 0; j < 4; j++) {
            tile[kk][c + j] = a[j] * wk;
            tile[kk][c + 4 + j] = b4[j] * wk;
        }
    }
    __syncthreads();
    {
        int d = t >> 2, kb2 = (t & 3) * 8;
        s16x8 o;
#pragma unroll
        for (int j = 0; j < 8; j++) o[j] = f2bf(tile[kb2 + j][d]);
        *(s16x8*)(vwt + ((size_t)bh * ND + d) * NS + k0 + kb2) = o;
    }
}

// ---------- main fused kernel ----------
// One WG = one (b,h) x 32 query rows. 8 waves (512 thr). LDS: P[32][2048] bf16
// XOR-swizzled (byte ^= (row&7)<<4) + (no-WS path) VT[64][128] bf16 + reduction.
template <bool WS>
__global__ __launch_bounds__(512, 1) void attn_main(
    const float* __restrict__ Qg, const float* __restrict__ Kg,
    const float* __restrict__ Vg, const int* __restrict__ maskg,
    const float* __restrict__ wg, const uint32_t* __restrict__ bitsg,
    const unsigned short* __restrict__ vwtg, float* __restrict__ outg,
    float* __restrict__ pg) {
    extern __shared__ char smem[];
    constexpr int P_BYTES = 32 * 4096;  // 128 KiB
    char* Pb = smem;
    char* VTb = smem + P_BYTES;
    float* red = (float*)(smem + P_BYTES + (WS ? 0 : 64 * 256));
    float* rinv_sh = red + 8 * 32;

    int bid = blockIdx.x;
    // XCD-aware swizzle (nwg=1536, %8==0 -> bijective): 3 heads per XCD L2
    int swz = (bid & 7) * (1536 / 8) + (bid >> 3);
    int bh = swz >> 6;
    int qt = swz & 63;
    int b = bh / NH;
    int q0 = qt * 32;

    const float* Qh = Qg + (size_t)bh * NS * ND;
    const float* Kh = Kg + (size_t)bh * NS * ND;
    const float* Vh = Vg + (size_t)bh * NS * ND;
    float* outh = outg + (size_t)bh * NS * ND;
    float* ph = pg + ((size_t)bh * NS + q0) * NS;
    const int* maskb = maskg + (size_t)b * NS * NS;
    const uint32_t* bitsb = bitsg + (size_t)b * (NS * (NS / 32));

    int tid = threadIdx.x;
    int wv = tid >> 6, lane = tid & 63;
    int m = lane & 15, kb = lane >> 4;

    // Q fragments (B operand of QK^T), 1/sqrt(64) folded in
    s16x8 qf[2][2];
#pragma unroll
    for (int n = 0; n < 2; n++)
#pragma unroll
        for (int ks = 0; ks < 2; ks++) {
            const float* src = Qh + (size_t)(q0 + n * 16 + m) * ND + ks * 32 + kb * 8;
            f32x4 a = *(const f32x4*)src;
            f32x4 c4 = *(const f32x4*)(src + 4);
            s16x8 f;
#pragma unroll
            for (int j = 0; j < 4; j++) {
                f[j] = f2bf(a[j] * 0.125f);
                f[4 + j] = f2bf(c4[j] * 0.125f);
            }
            qf[n][ks] = f;
        }

    // ---- Phase 1: scores = (K Q^T)/8, mask, relu -> P(bf16 LDS), ssum ----
    float ssum[2] = {0.f, 0.f};
    for (int kc = 0; kc < 16; kc++) {
        int k0 = kc * 128;
        int krow = k0 + wv * 16;
        s16x8 kf[2];
#pragma unroll
        for (int ks = 0; ks < 2; ks++) {
            const float* src = Kh + (size_t)(krow + m) * ND + ks * 32 + kb * 8;
            f32x4 a = *(const f32x4*)src;
            f32x4 c4 = *(const f32x4*)(src + 4);
            s16x8 f;
#pragma unroll
            for (int j = 0; j < 4; j++) {
                f[j] = f2bf(a[j]);
                f[4 + j] = f2bf(c4[j]);
            }
            kf[ks] = f;
        }
        f32x4 c0 = {0.f, 0.f, 0.f, 0.f}, c1 = {0.f, 0.f, 0.f, 0.f};
        c0 = mfma16(kf[0], qf[0][0], c0);
        c0 = mfma16(kf[1], qf[0][1], c0);
        c1 = mfma16(kf[0], qf[1][0], c1);
        c1 = mfma16(kf[1], qf[1][1], c1);

        int kcol = krow + kb * 4;  // 4 consecutive score columns per lane
#pragma unroll
        for (int n = 0; n < 2; n++) {
            f32x4 c = n ? c1 : c0;
            int ql = n * 16 + m;
            int qglob = q0 + ql;
            uint32_t keepbits;
            if (WS) {
                uint32_t word = bitsb[(size_t)qglob * (NS / 32) + (kcol >> 5)];
                keepbits = word >> (kcol & 31);
            } else {
                const int4 mi = *(const int4*)(maskb + (size_t)qglob * NS + kcol);
                keepbits = (uint32_t)(mi.x != 0) | ((uint32_t)(mi.y != 0) << 1) |
                           ((uint32_t)(mi.z != 0) << 2) | ((uint32_t)(mi.w != 0) << 3);
            }
            float p[4];
#pragma unroll
            for (int r = 0; r < 4; r++) {
                float s = c[r];
                bool keep = ((keepbits >> r) & 1u) && (s > 0.f);
                p[r] = keep ? s : 0.f;
            }
            ssum[n] += p[0] * p[0] + p[1] * p[1] + p[2] * p[2] + p[3] * p[3];
            uint32_t lo = (uint32_t)(unsigned short)f2bf(p[0]) |
                          ((uint32_t)(unsigned short)f2bf(p[1]) << 16);
            uint32_t hi = (uint32_t)(unsigned short)f2bf(p[2]) |
                          ((uint32_t)(unsigned short)f2bf(p[3]) << 16);
            int byte = ((ql * 4096) + kcol * 2) ^ ((ql & 7) << 4);
            uint2 u;
            u.x = lo;
            u.y = hi;
            *(uint2*)(Pb + byte) = u;
        }
    }

    // ---- row reduction -> 1/rms ----
    ssum[0] += __shfl_xor(ssum[0], 16);
    ssum[0] += __shfl_xor(ssum[0], 32);
    ssum[1] += __shfl_xor(ssum[1], 16);
    ssum[1] += __shfl_xor(ssum[1], 32);
    if (lane < 16) {
        red[wv * 32 + lane] = ssum[0];
        red[wv * 32 + 16 + lane] = ssum[1];
    }
    __syncthreads();
    if (tid < 32) {
        float s = 0.f;
#pragma unroll
        for (int i = 0; i < 8; i++) s += red[i * 32 + tid];
        rinv_sh[tid] = 1.0f / sqrtf(s * (1.0f / NS) + 1e-6f);
    }
    __syncthreads();

    // ---- Phase 2: stream p_attn = P * w * rinv (fp32, coalesced) ----
    {
        int col = (tid & 255) * 8;
        int rbase = tid >> 8;
        f32x4 w4a = *(const f32x4*)(wg + col);
        f32x4 w4b = *(const f32x4*)(wg + col + 4);
        for (int i = 0; i < 16; i++) {
            int r = i * 2 + rbase;
            float ri = rinv_sh[r];
            s16x8 pv = *(const s16x8*)(Pb + (((r * 4096) + col * 2) ^ ((r & 7) << 4)));
            f32x4 o1, o2;
#pragma unroll
            for (int j = 0; j < 4; j++) {
                o1[j] = bf2f(pv[j]) * w4a[j] * ri;
                o2[j] = bf2f(pv[4 + j]) * w4b[j] * ri;
            }
            float* dst = ph + (size_t)r * NS + col;
            *(f32x4*)dst = o1;
            *(f32x4*)(dst + 4) = o2;
        }
    }

    // ---- Phase 3: out^T[d][q] = sum_k VwT[d][k] * P[q][k] ----
    int mt = wv >> 2;
    int d0 = (wv & 3) * 16;
    f32x4 acc = {0.f, 0.f, 0.f, 0.f};
    for (int kc = 0; kc < 16; kc++) {
        int k0 = kc * 128;
        if (!WS) {
            __syncthreads();
#pragma unroll
            for (int i = 0; i < 4; i++) {
                int flat = tid + i * 512;
                int kk = flat >> 4;
                int c4 = (flat & 15) * 4;
                f32x4 v4 = *(const f32x4*)(Vh + (size_t)(k0 + kk) * ND + c4);
                float wk = wg[k0 + kk];
#pragma unroll
                for (int j = 0; j < 4; j++) {
                    int d = c4 + j;
                    int byte = (d * 256 + kk * 2) ^ ((d & 7) << 4);
                    *(unsigned short*)(VTb + byte) = (unsigned short)f2bf(v4[j] * wk);
                }
            }
            __syncthreads();
        }
#pragma unroll
        for (int ks = 0; ks < 4; ks++) {
            int koff = ks * 32 + kb * 8;
            s16x8 af;
            if (WS) {
                af = *(const s16x8*)(vwtg + ((size_t)bh * ND + d0 + m) * NS + k0 + koff);
            } else {
                int d = d0 + m;
                af = *(const s16x8*)(VTb + ((d * 256 + koff * 2) ^ ((d & 7) << 4)));
            }
            int q = mt * 16 + m;
            s16x8 bfr = *(const s16x8*)(Pb + ((q * 4096 + (k0 + koff) * 2) ^ ((q & 7) << 4)));
            acc = mfma16(af, bfr, acc);
        }
    }
    {
        int q = mt * 16 + m;
        float ri = rinv_sh[q];
        int dd = d0 + kb * 4;  // C row = (lane>>4)*4 + r -> d; col = lane&15 -> q
        f32x4 o;
#pragma unroll
        for (int r = 0; r < 4; r++) o[r] = acc[r] * ri;
        *(f32x4*)(outh + (size_t)(q0 + q) * ND + dd) = o;
    }
}

extern "C" void kernel_launch(void* const* d_in, const int* in_sizes, int n_in,
                              void* d_out, int out_size, void* d_ws, size_t ws_size,
                              hipStream_t stream) {
    const float* Q = (const float*)d_in[0];
    const float* K = (const float*)d_in[1];
    const float* V = (const float*)d_in[2];
    const int* mask = (const int*)d_in[3];
    const float* w = (const float*)d_in[4];
    float* out = (float*)d_out;
    float* pattn = out + (size_t)NB * NH * NS * ND;

    const size_t bits_bytes = (size_t)NB * NS * (NS / 32) * sizeof(uint32_t);  // 1 MB
    const size_t vwt_bytes = (size_t)NB * NH * ND * NS * sizeof(unsigned short);  // 6.3 MB
    const int nwg = NB * NH * (NS / 32);  // 1536

    if (ws_size >= bits_bytes + vwt_bytes) {
        uint32_t* bits = (uint32_t*)d_ws;
        unsigned short* vwt = (unsigned short*)((char*)d_ws + bits_bytes);
        kbits<<<(NB * NS * NS / 32) / 256, 256, 0, stream>>>(mask, bits);
        kvwt<<<NB * NH * (NS / 32), 256, 0, stream>>>(V, w, vwt);
        int smem = 32 * 4096 + (8 * 32 + 32) * 4;
        hipFuncSetAttribute(reinterpret_cast<const void*>(&attn_main<true>),
                            hipFuncAttributeMaxDynamicSharedMemorySize, smem);
        attn_main<true><<<nwg, 512, smem, stream>>>(Q, K, V, mask, w, bits, vwt, out, pattn);
    } else {
        int smem = 32 * 4096 + 64 * 256 + (8 * 32 + 32) * 4;
        hipFuncSetAttribute(reinterpret_cast<const void*>(&attn_main<false>),
                            hipFuncAttributeMaxDynamicSharedMemorySize, smem);
        attn_main<false><<<nwg, 512, smem, stream>>>(Q, K, V, mask, w, nullptr, nullptr, out,
                                                     pattn);
    }
}